// Round 1
// baseline (13.433 us; speedup 1.0000x reference)
//
#include <hip/hip_runtime.h>
#include <math.h>

#define NUM_EXPERTS 64
#define TOKENS 32768

__device__ __forceinline__ float wave_max(float v) {
#pragma unroll
    for (int off = 1; off < 64; off <<= 1)
        v = fmaxf(v, __shfl_xor(v, off));
    return v;
}

__global__ __launch_bounds__(256) void topk_gate_kernel(
    const float* __restrict__ routing, float* __restrict__ out, int rows) {
    int wave = (int)((blockIdx.x * blockDim.x + threadIdx.x) >> 6);
    int lane = (int)(threadIdx.x & 63);
    if (wave >= rows) return;

    const float orig = routing[wave * NUM_EXPERTS + lane];
    float v = orig;

    // 1st largest
    float m1 = wave_max(v);
    unsigned long long b1 = __ballot(v == m1);
    int f1 = __ffsll(b1) - 1;
    if (lane == f1) v = -INFINITY;

    // 2nd largest (s[62])
    float m2 = wave_max(v);
    unsigned long long b2 = __ballot(v == m2);
    int f2 = __ffsll(b2) - 1;
    if (lane == f2) v = -INFINITY;

    // 3rd largest (s[61])
    float m3 = wave_max(v);

    // linear-interp quantile at q = 1 - 2/64: pos = 61.03125
    float quant = m3 + 0.03125f * (m2 - m3);

    // mask = (orig > quant) ? orig : 0 ; out = round(mask / (mask + 0.01))
    float r = (orig > quant) ? rintf(orig / (orig + 0.01f)) : 0.0f;
    out[wave * NUM_EXPERTS + lane] = r;
}

extern "C" void kernel_launch(void* const* d_in, const int* in_sizes, int n_in,
                              void* d_out, int out_size, void* d_ws, size_t ws_size,
                              hipStream_t stream) {
    // d_in[0] = input [TOKENS, IN_FEATURES] (unused by the reference output)
    // d_in[1] = routing [TOKENS, NUM_EXPERTS] float32
    const float* routing = (const float*)d_in[1];
    float* out = (float*)d_out;

    int rows = in_sizes[1] / NUM_EXPERTS;  // 32768
    // one 64-lane wave per row; 4 rows per 256-thread block
    int blocks = (rows + 3) / 4;
    topk_gate_kernel<<<blocks, 256, 0, stream>>>(routing, out, rows);
}

// Round 2
// 10.445 us; speedup vs baseline: 1.2860x; 1.2860x over previous
//
#include <hip/hip_runtime.h>
#include <math.h>

#define NUM_EXPERTS 64
#define LANES_PER_ROW 16   // 4 floats per lane

// Insert x into descending-sorted triple (t1 >= t2 >= t3), keep top-3.
__device__ __forceinline__ void insert3(float& t1, float& t2, float& t3, float x) {
    float l1 = fminf(t1, x);
    t1 = fmaxf(t1, x);
    float l2 = fminf(t2, l1);
    t2 = fmaxf(t2, l1);
    t3 = fmaxf(t3, l2);
}

__global__ __launch_bounds__(256) void topk_gate_v2(
    const float4* __restrict__ routing4, float4* __restrict__ out4, int nvec) {
    int idx = blockIdx.x * blockDim.x + threadIdx.x;  // float4 index = row*16 + sub
    if (idx >= nvec) return;

    float4 e = routing4[idx];

    // local top-3 of this lane's 4 elements
    float t1 = e.x, t2 = -INFINITY, t3 = -INFINITY;
    insert3(t1, t2, t3, e.y);
    insert3(t1, t2, t3, e.z);
    insert3(t1, t2, t3, e.w);

    // butterfly merge across the 16 lanes owning this row (xor masks stay in group)
#pragma unroll
    for (int off = 1; off < LANES_PER_ROW; off <<= 1) {
        float b1 = __shfl_xor(t1, off);
        float b2 = __shfl_xor(t2, off);
        float b3 = __shfl_xor(t3, off);
        // merge sorted triple (b1>=b2>=b3) into (t1,t2,t3)
        // insert b1 (full)
        float l1 = fminf(t1, b1);
        t1 = fmaxf(t1, b1);
        float l2 = fminf(t2, l1);
        t2 = fmaxf(t2, l1);
        t3 = fmaxf(t3, l2);
        // insert b2 (b2 <= b1 <= t1, so skip t1 slot)
        float l3 = fminf(t2, b2);
        t2 = fmaxf(t2, b2);
        t3 = fmaxf(t3, l3);
        // insert b3 (b3 <= b2 <= t2, so skip t1,t2 slots)
        t3 = fmaxf(t3, b3);
    }

    // t1 = s[63], t2 = s[62], t3 = s[61]; quantile pos 61.03125
    float quant = t3 + 0.03125f * (t2 - t3);

    float4 r;
    r.x = (e.x > quant) ? rintf(e.x / (e.x + 0.01f)) : 0.0f;
    r.y = (e.y > quant) ? rintf(e.y / (e.y + 0.01f)) : 0.0f;
    r.z = (e.z > quant) ? rintf(e.z / (e.z + 0.01f)) : 0.0f;
    r.w = (e.w > quant) ? rintf(e.w / (e.w + 0.01f)) : 0.0f;
    out4[idx] = r;
}

extern "C" void kernel_launch(void* const* d_in, const int* in_sizes, int n_in,
                              void* d_out, int out_size, void* d_ws, size_t ws_size,
                              hipStream_t stream) {
    // d_in[0] = input (unused), d_in[1] = routing [TOKENS, 64] float32
    const float4* routing4 = (const float4*)d_in[1];
    float4* out4 = (float4*)d_out;

    int nvec = in_sizes[1] / 4;            // 524288 float4s (16 per row)
    int blocks = (nvec + 255) / 256;       // 2048 blocks
    topk_gate_v2<<<blocks, 256, 0, stream>>>(routing4, out4, nvec);
}